// Round 3
// baseline (560.785 us; speedup 1.0000x reference)
//
#include <hip/hip_runtime.h>
#include <hip/hip_bf16.h>

// Problem constants
#define TT 128
#define EE 192
#define HH 192
#define SCALE_F 0.07216878364870322f
#define LOG2E_F 1.4426950408889634f

typedef float f32x4 __attribute__((ext_vector_type(4)));
typedef short short8 __attribute__((ext_vector_type(8)));
typedef short short4v __attribute__((ext_vector_type(4)));

__device__ inline unsigned short f2bf(float x) {
  union { float f; unsigned u; } v; v.f = x;
  unsigned r = v.u + 0x7FFFu + ((v.u >> 16) & 1u);
  return (unsigned short)(r >> 16);
}

// ---------------------------------------------------------------------------
// kernel 0: weights fp32 -> bf16, contiguous [576][192] rows (Q rows 0-191,
// K rows 192-383, V rows 384-575).
// ---------------------------------------------------------------------------
__global__ void cvt_w(const float* __restrict__ Wq, const float* __restrict__ Wk,
                      const float* __restrict__ Wv, short* __restrict__ out) {
  int idx = blockIdx.x * 256 + threadIdx.x;  // float4 index, 27648 total
  const float* src; int base;
  if (idx < 9216) { src = Wq; base = 0; }
  else if (idx < 18432) { src = Wk; base = 9216; }
  else { src = Wv; base = 18432; }
  float4 f = ((const float4*)src)[idx - base];
  short4v h;
  h[0] = (short)f2bf(f.x); h[1] = (short)f2bf(f.y);
  h[2] = (short)f2bf(f.z); h[3] = (short)f2bf(f.w);
  *(short4v*)(out + idx * 4) = h;
}

// ---------------------------------------------------------------------------
// K1: QKV projection. Block = half a batch (64 rows) x all 576 out-cols.
// 512 thr (8 waves) = 2 m-groups (32 rows) x 4 n-groups (144 cols = 9 tiles).
// Outputs: Q bf16 [b][128][192] -> qout (ws); K bf16 [b][128][192] and
// V^T bf16 [b][192][128] -> kvout (= d_out region, 49152+49152 bytes/batch).
// ---------------------------------------------------------------------------
__global__ __launch_bounds__(512, 4)
void qkv_kernel(const float* __restrict__ x, const short* __restrict__ wb,
                char* __restrict__ qout, char* __restrict__ kvout) {
  extern __shared__ char xs[];  // [64][192] bf16, row stride 400 B (25600 B)
  const int bh = blockIdx.x, b = bh >> 1, half = bh & 1;
  const int tid = threadIdx.x;
  const int wid = tid >> 6, lane = tid & 63, lg = lane >> 4, lr = lane & 15;
  const int mg = wid >> 2, ng = wid & 3;

  // stage x rows [64*half, 64*half+64) -> LDS bf16
  const float4* xb4 = (const float4*)(x + (size_t)b * (TT * EE) + (size_t)half * 64 * EE);
#pragma unroll
  for (int i = 0; i < 6; ++i) {
    int fi = tid + i * 512;           // 3072 float4 total
    float4 f = xb4[fi];
    int row = fi / 48, c4 = fi % 48;
    short4v h4;
    h4[0] = (short)f2bf(f.x); h4[1] = (short)f2bf(f.y);
    h4[2] = (short)f2bf(f.z); h4[3] = (short)f2bf(f.w);
    *(short4v*)(xs + row * 400 + c4 * 8) = h4;
  }
  __syncthreads();

  f32x4 acc[2][9];
  const f32x4 zero = {0.f, 0.f, 0.f, 0.f};
#pragma unroll
  for (int at = 0; at < 2; ++at)
#pragma unroll
    for (int nt = 0; nt < 9; ++nt) acc[at][nt] = zero;

  const char* wbc = (const char*)wb;
#pragma unroll
  for (int kt = 0; kt < 6; ++kt) {
    short8 a0 = *(const short8*)(xs + (mg * 32 + lr) * 400 + kt * 64 + lg * 16);
    short8 a1 = *(const short8*)(xs + (mg * 32 + 16 + lr) * 400 + kt * 64 + lg * 16);
#pragma unroll
    for (int nt = 0; nt < 9; ++nt) {
      int c = ng * 144 + nt * 16;   // global out-col (weight row) base
      short8 bw = *(const short8*)(wbc + (size_t)(c + lr) * 384 + kt * 64 + lg * 16);
      acc[0][nt] = __builtin_amdgcn_mfma_f32_16x16x32_bf16(a0, bw, acc[0][nt], 0, 0, 0);
      acc[1][nt] = __builtin_amdgcn_mfma_f32_16x16x32_bf16(a1, bw, acc[1][nt], 0, 0, 0);
    }
  }

  const size_t bq = (size_t)b * 49152;
  const size_t bkv = (size_t)b * 98304;
#pragma unroll
  for (int at = 0; at < 2; ++at) {
    int t0 = half * 64 + mg * 32 + at * 16 + 4 * lg;  // + r
#pragma unroll
    for (int nt = 0; nt < 9; ++nt) {
      int c = ng * 144 + nt * 16;
      int mat = (c >= 384) ? 2 : ((c >= 192) ? 1 : 0);
      int cc = c - mat * 192;
      if (mat == 2) {
        short4v p;
        p[0] = (short)f2bf(acc[at][nt][0]); p[1] = (short)f2bf(acc[at][nt][1]);
        p[2] = (short)f2bf(acc[at][nt][2]); p[3] = (short)f2bf(acc[at][nt][3]);
        *(short4v*)(kvout + bkv + 49152 + (size_t)(cc + lr) * 256 + t0 * 2) = p;
      } else {
        char* base = mat ? (kvout + bkv) : (qout + bq);
#pragma unroll
        for (int r = 0; r < 4; ++r)
          *(unsigned short*)(base + (size_t)(t0 + r) * 384 + (cc + lr) * 2) =
              f2bf(acc[at][nt][r]);
      }
    }
  }
}

// ---------------------------------------------------------------------------
// K2: attention, LDS-free. Block = 1 batch, 8 waves, wave = q-tile (16 rows).
// S^T via mfma(K, Q) so each lane holds one q-row's scores (q = lr):
//   D lane(lg,lr): S^T[k=16kt+4lg+r][q=16qt+lr].
// Softmax in-lane + 2 shfl_xor. P redistributed to PV A-fragments by register
// shuffles. Reads Q(ws), K/V^T(d_out); after a barrier overwrites d_out with out.
// ---------------------------------------------------------------------------
__global__ __launch_bounds__(512, 4)
void attn_kernel(const char* __restrict__ qbuf, char* kvbuf, float* out) {
  const int b = blockIdx.x;
  const int tid = threadIdx.x;
  const int qt = tid >> 6, lane = tid & 63, lg = lane >> 4, lr = lane & 15;
  const char* qb = qbuf + (size_t)b * 49152;
  const char* kb = kvbuf + (size_t)b * 98304;
  const char* vb = kb + 49152;

  // Q B-fragments: lane -> Q[16qt+lr][32s + 8lg + j]
  short8 q[6];
#pragma unroll
  for (int s = 0; s < 6; ++s)
    q[s] = *(const short8*)(qb + (16 * qt + lr) * 384 + s * 64 + lg * 16);

  // QK^T (transposed): sa[kt] = S^T tile
  f32x4 sa[8];
  const f32x4 zero = {0.f, 0.f, 0.f, 0.f};
#pragma unroll
  for (int kt = 0; kt < 8; ++kt) sa[kt] = zero;
#pragma unroll
  for (int kt = 0; kt < 8; ++kt) {
    if (kt <= qt) {
#pragma unroll
      for (int s = 0; s < 6; ++s) {
        short8 ka = *(const short8*)(kb + (16 * kt + lr) * 384 + s * 64 + lg * 16);
        sa[kt] = __builtin_amdgcn_mfma_f32_16x16x32_bf16(ka, q[s], sa[kt], 0, 0, 0);
      }
    }
  }

  // softmax over row q = 16qt+lr (values: kt<=qt, r=0..3, spread over 4 lg-lanes)
  const float CSC = SCALE_F * LOG2E_F;
  float m = -INFINITY;
#pragma unroll
  for (int kt = 0; kt < 8; ++kt)
    if (kt <= qt) {
#pragma unroll
      for (int r = 0; r < 4; ++r) {
        float v = sa[kt][r] * CSC;
        if (kt == qt && 4 * lg + r > lr) v = -INFINITY;  // causal diagonal
        sa[kt][r] = v;
        m = fmaxf(m, v);
      }
    }
  m = fmaxf(m, __shfl_xor(m, 16));
  m = fmaxf(m, __shfl_xor(m, 32));
  float sum = 0.f;
#pragma unroll
  for (int kt = 0; kt < 8; ++kt)
    if (kt <= qt) {
#pragma unroll
      for (int r = 0; r < 4; ++r) {
        float p = exp2f(sa[kt][r] - m);
        sa[kt][r] = p;
        sum += p;
      }
    }
  sum += __shfl_xor(sum, 16);
  sum += __shfl_xor(sum, 32);
  const float rinv = 1.0f / sum;

  // pack normalized P to bf16 pairs: w[kt][0]=(r0,r1), w[kt][1]=(r2,r3)
  unsigned w[8][2];
#pragma unroll
  for (int kt = 0; kt < 8; ++kt) { w[kt][0] = 0u; w[kt][1] = 0u; }
#pragma unroll
  for (int kt = 0; kt < 8; ++kt)
    if (kt <= qt) {
      w[kt][0] = (unsigned)f2bf(sa[kt][0] * rinv) |
                 ((unsigned)f2bf(sa[kt][1] * rinv) << 16);
      w[kt][1] = (unsigned)f2bf(sa[kt][2] * rinv) |
                 ((unsigned)f2bf(sa[kt][3] * rinv) << 16);
    }

  // PV: A-frag lane(lg,lr) j -> P[q=16qt+lr][t=32ktp+8lg+j]
  //   source: lane(lg_s = 2*(lg&1) + (j>>2), lr), tile kt_s = 2ktp + (lg>>1)
  f32x4 o[12];
#pragma unroll
  for (int ht = 0; ht < 12; ++ht) o[ht] = zero;
#pragma unroll
  for (int ktp = 0; ktp < 4; ++ktp) {
    if (ktp <= (qt >> 1)) {
      union { unsigned d[4]; short8 v; } au;
#pragma unroll
      for (int i = 0; i < 4; ++i) {
        int wi = i & 1, bsel = i >> 1;
        int sl = ((2 * (lg & 1) + bsel) << 4) | lr;
        unsigned lo = (unsigned)__shfl((int)w[2 * ktp][wi], sl);
        unsigned hi = (unsigned)__shfl((int)w[2 * ktp + 1][wi], sl);
        au.d[i] = (lg >> 1) ? hi : lo;
      }
      short8 a = au.v;
#pragma unroll
      for (int ht = 0; ht < 12; ++ht) {
        short8 bv = *(const short8*)(vb + (16 * ht + lr) * 256 + ktp * 64 + lg * 16);
        o[ht] = __builtin_amdgcn_mfma_f32_16x16x32_bf16(a, bv, o[ht], 0, 0, 0);
      }
    }
  }

  __syncthreads();  // all K/V reads complete before overwriting d_out[b]

  float* ob = out + (size_t)b * (TT * HH);
#pragma unroll
  for (int ht = 0; ht < 12; ++ht)
#pragma unroll
    for (int r = 0; r < 4; ++r)
      ob[(16 * qt + 4 * lg + r) * HH + 16 * ht + lr] = o[ht][r];
}

// ---------------------------------------------------------------------------
// Fallback: round-1 fused kernel (used only if ws is too small for Q+weights)
// ---------------------------------------------------------------------------
#define XO 0
#define XS 400
#define KO 51200
#define VO 102400
#define VS 272
#define PS 272
#define LDS_TOTAL 154624

__device__ inline void fb_proj(const float* __restrict__ W, const char* xs,
                               int ns, int mh, int lg, int lr, f32x4 acc[4][3]) {
  const f32x4 zero = {0.f, 0.f, 0.f, 0.f};
#pragma unroll
  for (int mt = 0; mt < 4; ++mt)
#pragma unroll
    for (int nt = 0; nt < 3; ++nt) acc[mt][nt] = zero;
#pragma unroll
  for (int kt = 0; kt < 6; ++kt) {
    int e0 = kt * 32 + lg * 8;
    short8 bfr[3];
#pragma unroll
    for (int nt = 0; nt < 3; ++nt) {
      int h = ns * 48 + nt * 16 + lr;
      const float* wp = W + h * EE + e0;
      float4 f0 = *(const float4*)wp;
      float4 f1 = *(const float4*)(wp + 4);
      short8 bb;
      bb[0] = (short)f2bf(f0.x); bb[1] = (short)f2bf(f0.y);
      bb[2] = (short)f2bf(f0.z); bb[3] = (short)f2bf(f0.w);
      bb[4] = (short)f2bf(f1.x); bb[5] = (short)f2bf(f1.y);
      bb[6] = (short)f2bf(f1.z); bb[7] = (short)f2bf(f1.w);
      bfr[nt] = bb;
    }
#pragma unroll
    for (int mt = 0; mt < 4; ++mt) {
      int t = mh * 64 + mt * 16 + lr;
      short8 a = *(const short8*)(xs + t * XS + e0 * 2);
#pragma unroll
      for (int nt = 0; nt < 3; ++nt)
        acc[mt][nt] = __builtin_amdgcn_mfma_f32_16x16x32_bf16(a, bfr[nt], acc[mt][nt], 0, 0, 0);
    }
  }
}

__global__ __launch_bounds__(512, 2)
void fused_kernel(const float* __restrict__ x, const float* __restrict__ Wq,
                  const float* __restrict__ Wk, const float* __restrict__ Wv,
                  float* __restrict__ out) {
  extern __shared__ char smem[];
  const int b = blockIdx.x;
  const int tid = threadIdx.x;
  const int wid = tid >> 6, lane = tid & 63;
  const int lg = lane >> 4, lr = lane & 15;
  const int ns = wid >> 1, mh = wid & 1;

  const float4* xb4 = (const float4*)(x + (size_t)b * (TT * EE));
#pragma unroll
  for (int i = 0; i < 12; ++i) {
    int fi = tid + i * 512;
    float4 f = xb4[fi];
    int row = fi / 48, c4 = fi % 48;
    short4v h4;
    h4[0] = (short)f2bf(f.x); h4[1] = (short)f2bf(f.y);
    h4[2] = (short)f2bf(f.z); h4[3] = (short)f2bf(f.w);
    *(short4v*)(smem + XO + row * XS + c4 * 8) = h4;
  }
  __syncthreads();

  f32x4 acc[4][3];
  fb_proj(Wk, smem + XO, ns, mh, lg, lr, acc);
#pragma unroll
  for (int mt = 0; mt < 4; ++mt)
#pragma unroll
    for (int nt = 0; nt < 3; ++nt) {
      int h = ns * 48 + nt * 16 + lr;
#pragma unroll
      for (int r = 0; r < 4; ++r) {
        int t = mh * 64 + mt * 16 + lg * 4 + r;
        *(unsigned short*)(smem + KO + t * XS + h * 2) = f2bf(acc[mt][nt][r]);
      }
    }
  fb_proj(Wv, smem + XO, ns, mh, lg, lr, acc);
#pragma unroll
  for (int mt = 0; mt < 4; ++mt)
#pragma unroll
    for (int nt = 0; nt < 3; ++nt) {
      int h = ns * 48 + nt * 16 + lr;
      int t0 = mh * 64 + mt * 16 + lg * 4;
      short4v p;
      p[0] = (short)f2bf(acc[mt][nt][0]); p[1] = (short)f2bf(acc[mt][nt][1]);
      p[2] = (short)f2bf(acc[mt][nt][2]); p[3] = (short)f2bf(acc[mt][nt][3]);
      *(short4v*)(smem + VO + h * VS + t0 * 2) = p;
    }
  fb_proj(Wq, smem + XO, ns, mh, lg, lr, acc);
  __syncthreads();
#pragma unroll
  for (int mt = 0; mt < 4; ++mt)
#pragma unroll
    for (int nt = 0; nt < 3; ++nt) {
      int h = ns * 48 + nt * 16 + lr;
#pragma unroll
      for (int r = 0; r < 4; ++r) {
        int t = mh * 64 + mt * 16 + lg * 4 + r;
        *(unsigned short*)(smem + XO + t * XS + h * 2) = f2bf(acc[mt][nt][r]);
      }
    }
  __syncthreads();

  const int qt = wid;
  f32x4 s[8];
  const f32x4 zero = {0.f, 0.f, 0.f, 0.f};
#pragma unroll
  for (int nt = 0; nt < 8; ++nt) s[nt] = zero;
#pragma unroll
  for (int kt = 0; kt < 6; ++kt) {
    int e0 = kt * 32 + lg * 8;
    short8 a = *(const short8*)(smem + XO + (qt * 16 + lr) * XS + e0 * 2);
#pragma unroll
    for (int nt = 0; nt < 8; ++nt) {
      short8 bb = *(const short8*)(smem + KO + (nt * 16 + lr) * XS + e0 * 2);
      s[nt] = __builtin_amdgcn_mfma_f32_16x16x32_bf16(a, bb, s[nt], 0, 0, 0);
    }
  }
  const float CSC = SCALE_F * LOG2E_F;
  float pv[4][8];
  float rinv[4];
#pragma unroll
  for (int r = 0; r < 4; ++r) {
    int qq = qt * 16 + lg * 4 + r;
    float mx = -INFINITY;
#pragma unroll
    for (int nt = 0; nt < 8; ++nt) {
      int c = nt * 16 + lr;
      float v = s[nt][r] * CSC;
      v = (c <= qq) ? v : -INFINITY;
      pv[r][nt] = v;
      mx = fmaxf(mx, v);
    }
    mx = fmaxf(mx, __shfl_xor(mx, 1));
    mx = fmaxf(mx, __shfl_xor(mx, 2));
    mx = fmaxf(mx, __shfl_xor(mx, 4));
    mx = fmaxf(mx, __shfl_xor(mx, 8));
    float su = 0.f;
#pragma unroll
    for (int nt = 0; nt < 8; ++nt) {
      float p = exp2f(pv[r][nt] - mx);
      pv[r][nt] = p;
      su += p;
    }
    su += __shfl_xor(su, 1);
    su += __shfl_xor(su, 2);
    su += __shfl_xor(su, 4);
    su += __shfl_xor(su, 8);
    rinv[r] = 1.0f / su;
  }
  __syncthreads();
#pragma unroll
  for (int r = 0; r < 4; ++r) {
    int qq = qt * 16 + lg * 4 + r;
#pragma unroll
    for (int nt = 0; nt < 8; ++nt)
      *(unsigned short*)(smem + XO + qq * PS + (nt * 16 + lr) * 2) = f2bf(pv[r][nt] * rinv[r]);
  }
  __syncthreads();
  f32x4 o[12];
#pragma unroll
  for (int nt = 0; nt < 12; ++nt) o[nt] = zero;
#pragma unroll
  for (int kt = 0; kt < 4; ++kt) {
    int t0 = kt * 32 + lg * 8;
    short8 a = *(const short8*)(smem + XO + (qt * 16 + lr) * PS + t0 * 2);
#pragma unroll
    for (int nt = 0; nt < 12; ++nt) {
      short8 bb = *(const short8*)(smem + VO + (nt * 16 + lr) * VS + t0 * 2);
      o[nt] = __builtin_amdgcn_mfma_f32_16x16x32_bf16(a, bb, o[nt], 0, 0, 0);
    }
  }
  float* ob = out + (size_t)b * (TT * HH);
#pragma unroll
  for (int nt = 0; nt < 12; ++nt)
#pragma unroll
    for (int r = 0; r < 4; ++r) {
      int qq = qt * 16 + lg * 4 + r;
      ob[qq * HH + nt * 16 + lr] = o[nt][r];
    }
}

extern "C" void kernel_launch(void* const* d_in, const int* in_sizes, int n_in,
                              void* d_out, int out_size, void* d_ws, size_t ws_size,
                              hipStream_t stream) {
  const float* x  = (const float*)d_in[0];
  const float* Wq = (const float*)d_in[1];
  const float* Wk = (const float*)d_in[2];
  const float* Wv = (const float*)d_in[3];
  int Bn = in_sizes[0] / (TT * EE);

  size_t qbytes = (size_t)Bn * 49152;      // Q bf16 region in ws
  size_t need = qbytes + 221184;           // + bf16 weights

  if (ws_size >= need) {
    short* wb = (short*)((char*)d_ws + qbytes);
    hipLaunchKernelGGL(cvt_w, dim3(108), dim3(256), 0, stream, Wq, Wk, Wv, wb);
    hipLaunchKernelGGL(qkv_kernel, dim3(2 * Bn), dim3(512), 25600, stream,
                       x, wb, (char*)d_ws, (char*)d_out);
    hipLaunchKernelGGL(attn_kernel, dim3(Bn), dim3(512), 0, stream,
                       (const char*)d_ws, (char*)d_out, (float*)d_out);
  } else {
    hipLaunchKernelGGL(fused_kernel, dim3(Bn), dim3(512), LDS_TOTAL, stream,
                       x, Wq, Wk, Wv, (float*)d_out);
  }
}

// Round 4
// 528.423 us; speedup vs baseline: 1.0612x; 1.0612x over previous
//
#include <hip/hip_runtime.h>

// Problem constants
#define TT 128
#define EE 192
#define HH 192
#define SCALE_F 0.07216878364870322f
#define LOG2E_F 1.4426950408889634f

typedef float f32x4 __attribute__((ext_vector_type(4)));
typedef short short8 __attribute__((ext_vector_type(8)));

__device__ inline unsigned short f2bf(float x) {
  union { float f; unsigned u; } v; v.f = x;
  unsigned r = v.u + 0x7FFFu + ((v.u >> 16) & 1u);
  return (unsigned short)(r >> 16);
}
__device__ inline unsigned pack2bf(float a, float b) {
  return (unsigned)f2bf(a) | ((unsigned)f2bf(b) << 16);
}

// ---------------------------------------------------------------------------
// pack_w: W[h][e] fp32 -> frag-major bf16 in ws.
// frag f = widx*72 + tile*6 + es  (widx: 0=Q,1=K,2=V; tile=h/16; es=e/32)
// element: lane(lg,lr), j=0..7 -> W[16*tile+lr][32*es+8*lg+j]
// Each frag is 1KB contiguous: ws[(f*64+lane)*8 + j]
// ---------------------------------------------------------------------------
__global__ void pack_w(const float* __restrict__ Wq, const float* __restrict__ Wk,
                       const float* __restrict__ Wv, short* __restrict__ out) {
  int f = blockIdx.x * 4 + (threadIdx.x >> 6);  // 216 frags, grid 54 x 256
  int lane = threadIdx.x & 63, lg = lane >> 4, lr = lane & 15;
  int widx = f / 72, rem = f % 72, tile = rem / 6, es = rem % 6;
  const float* W = (widx == 0) ? Wq : ((widx == 1) ? Wk : Wv);
  const float* p = W + (16 * tile + lr) * EE + 32 * es + 8 * lg;
  float4 a = *(const float4*)p;
  float4 b = *(const float4*)(p + 4);
  short8 h;
  h[0] = (short)f2bf(a.x); h[1] = (short)f2bf(a.y);
  h[2] = (short)f2bf(a.z); h[3] = (short)f2bf(a.w);
  h[4] = (short)f2bf(b.x); h[5] = (short)f2bf(b.y);
  h[6] = (short)f2bf(b.z); h[7] = (short)f2bf(b.w);
  *(short8*)(out + ((size_t)f * 64 + lane) * 8) = h;
}

// ---------------------------------------------------------------------------
// Fused head kernel. Block = 1 batch, 512 thr (8 waves), 48KB LDS, 3 barriers.
// LDS holds K as QK^T A-fragments [kt 0..7][ha 0..5] (48 x 1KB), then (after
// B2) V as PV B-fragments [tp 0..3][ht 0..11] (48 x 1KB).
// Wave wid: q-tile qt=wid; staging m-tiles {wid, wid^4} x n-slab (wid>>2)*6.
// ---------------------------------------------------------------------------
__global__ __launch_bounds__(512, 4)
void head_fused(const float* __restrict__ x, const short* __restrict__ wf,
                float* __restrict__ out) {
  extern __shared__ char smem[];  // 49152 B
  const int b = blockIdx.x;
  const int tid = threadIdx.x;
  const int wid = tid >> 6, lane = tid & 63, lg = lane >> 4, lr = lane & 15;
  const int qt = wid;
  const int ns0 = (wid >> 2) * 6;  // staging n-slab

  const short* wfq = wf;
  const short* wfk = wf + 72 * 64 * 8;
  const short* wfv = wf + 2 * 72 * 64 * 8;
  const f32x4 zero = {0.f, 0.f, 0.f, 0.f};

  // ---- x fragments: xq = rows 16*wid+lr (own q-rows), xo = rows 16*(wid^4)+lr
  const float* xb = x + (size_t)b * (TT * EE);
  short8 xq[6], xo[6];
#pragma unroll
  for (int es = 0; es < 6; ++es) {
    const float* p = xb + (16 * wid + lr) * EE + 32 * es + 8 * lg;
    float4 u = *(const float4*)p, v = *(const float4*)(p + 4);
    short8 h;
    h[0] = (short)f2bf(u.x); h[1] = (short)f2bf(u.y);
    h[2] = (short)f2bf(u.z); h[3] = (short)f2bf(u.w);
    h[4] = (short)f2bf(v.x); h[5] = (short)f2bf(v.y);
    h[6] = (short)f2bf(v.z); h[7] = (short)f2bf(v.w);
    xq[es] = h;
    const float* p2 = xb + (16 * (wid ^ 4) + lr) * EE + 32 * es + 8 * lg;
    float4 u2 = *(const float4*)p2, v2 = *(const float4*)(p2 + 4);
    short8 h2;
    h2[0] = (short)f2bf(u2.x); h2[1] = (short)f2bf(u2.y);
    h2[2] = (short)f2bf(u2.z); h2[3] = (short)f2bf(u2.w);
    h2[4] = (short)f2bf(v2.x); h2[5] = (short)f2bf(v2.y);
    h2[6] = (short)f2bf(v2.z); h2[7] = (short)f2bf(v2.w);
    xo[es] = h2;
  }

  // ---- Q^T = mfma(A=Wq-frag, B=xq): lane holds Q^T[16ht+4lg+r][16qt+lr]
  unsigned wqp[12][2];
#pragma unroll
  for (int ht = 0; ht < 12; ++ht) {
    f32x4 a = zero;
#pragma unroll
    for (int es = 0; es < 6; ++es) {
      short8 wg = *(const short8*)(wfq + ((size_t)(ht * 6 + es) * 64 + lane) * 8);
      a = __builtin_amdgcn_mfma_f32_16x16x32_bf16(wg, xq[es], a, 0, 0, 0);
    }
    wqp[ht][0] = pack2bf(a[0], a[1]);
    wqp[ht][1] = pack2bf(a[2], a[3]);
  }

  // ---- build QK B-fragments qb[ha]: lane j -> Q[16qt+lr][32ha+8lg+j]
  short8 qb[6];
#pragma unroll
  for (int ha = 0; ha < 6; ++ha) {
    union { unsigned d[4]; short8 v; } au;
#pragma unroll
    for (int i = 0; i < 4; ++i) {
      int sl = ((2 * (lg & 1) + (i >> 1)) << 4) | lr;
      unsigned v0 = (unsigned)__shfl((int)wqp[2 * ha][i & 1], sl);
      unsigned v1 = (unsigned)__shfl((int)wqp[2 * ha + 1][i & 1], sl);
      au.d[i] = (lg >> 1) ? v1 : v0;
    }
    qb[ha] = au.v;
  }

  // ---- K staging: tiles (mt=wid, nt) with xq and (mt=wid^4, nt) with xo ----
#pragma unroll
  for (int n6 = 0; n6 < 6; ++n6) {
    int nt = ns0 + n6;
    f32x4 a0 = zero, a1 = zero;
#pragma unroll
    for (int es = 0; es < 6; ++es) {
      short8 wg = *(const short8*)(wfk + ((size_t)(nt * 6 + es) * 64 + lane) * 8);
      a0 = __builtin_amdgcn_mfma_f32_16x16x32_bf16(xq[es], wg, a0, 0, 0, 0);
      a1 = __builtin_amdgcn_mfma_f32_16x16x32_bf16(xo[es], wg, a1, 0, 0, 0);
    }
    // value K[16mt+4lg+r][16nt+lr] -> A-frag(kt=mt, ha=nt>>1):
    //   dest lane (lg2=2(nt&1)+(lr>>3), lr2=4lg+r), byte j=lr&7
    int lg2 = 2 * (nt & 1) + (lr >> 3), j = lr & 7;
#pragma unroll
    for (int r = 0; r < 4; ++r) {
      *(unsigned short*)(smem +
        (((wid * 6 + (nt >> 1)) * 64 + lg2 * 16 + 4 * lg + r) << 4) + j * 2) = f2bf(a0[r]);
      *(unsigned short*)(smem +
        ((((wid ^ 4) * 6 + (nt >> 1)) * 64 + lg2 * 16 + 4 * lg + r) << 4) + j * 2) = f2bf(a1[r]);
    }
  }
  __syncthreads();  // B1: K fragments visible

  // ---- QK^T (S^T = mfma(K, Q)): lane holds S^T[16kt+4lg+r][16qt+lr] ----
  f32x4 sa[8];
#pragma unroll
  for (int kt = 0; kt < 8; ++kt) sa[kt] = zero;
#pragma unroll
  for (int kt = 0; kt < 8; ++kt) {
    if (kt <= qt) {
#pragma unroll
      for (int ha = 0; ha < 6; ++ha) {
        short8 ka = *(const short8*)(smem + (((kt * 6 + ha) * 64 + lane) << 4));
        sa[kt] = __builtin_amdgcn_mfma_f32_16x16x32_bf16(ka, qb[ha], sa[kt], 0, 0, 0);
      }
    }
  }

  // ---- softmax over row q=16qt+lr (in-lane + 2 shfl_xor across lg) ----
  const float CSC = SCALE_F * LOG2E_F;
  float m = -INFINITY;
#pragma unroll
  for (int kt = 0; kt < 8; ++kt)
    if (kt <= qt) {
#pragma unroll
      for (int r = 0; r < 4; ++r) {
        float v = sa[kt][r] * CSC;
        if (kt == qt && 4 * lg + r > lr) v = -INFINITY;  // causal diagonal
        sa[kt][r] = v;
        m = fmaxf(m, v);
      }
    }
  m = fmaxf(m, __shfl_xor(m, 16));
  m = fmaxf(m, __shfl_xor(m, 32));
  float sum = 0.f;
#pragma unroll
  for (int kt = 0; kt < 8; ++kt)
    if (kt <= qt) {
#pragma unroll
      for (int r = 0; r < 4; ++r) {
        float p = exp2f(sa[kt][r] - m);
        sa[kt][r] = p;
        sum += p;
      }
    }
  sum += __shfl_xor(sum, 16);
  sum += __shfl_xor(sum, 32);
  const float rinv = 1.0f / sum;

  unsigned pw[8][2];
#pragma unroll
  for (int kt = 0; kt < 8; ++kt) { pw[kt][0] = 0u; pw[kt][1] = 0u; }
#pragma unroll
  for (int kt = 0; kt < 8; ++kt)
    if (kt <= qt) {
      pw[kt][0] = pack2bf(sa[kt][0] * rinv, sa[kt][1] * rinv);
      pw[kt][1] = pack2bf(sa[kt][2] * rinv, sa[kt][3] * rinv);
    }
  __syncthreads();  // B2: all K-fragment reads done; LDS reusable for V

  // ---- V staging into PV B-fragments [tp][ht] ----
#pragma unroll
  for (int n6 = 0; n6 < 6; ++n6) {
    int nt = ns0 + n6;
    f32x4 a0 = zero, a1 = zero;
#pragma unroll
    for (int es = 0; es < 6; ++es) {
      short8 wg = *(const short8*)(wfv + ((size_t)(nt * 6 + es) * 64 + lane) * 8);
      a0 = __builtin_amdgcn_mfma_f32_16x16x32_bf16(xq[es], wg, a0, 0, 0, 0);
      a1 = __builtin_amdgcn_mfma_f32_16x16x32_bf16(xo[es], wg, a1, 0, 0, 0);
    }
    // value V[16mt+4lg+r][16nt+lr] -> B-frag(tp=mt>>1, ht=nt):
    //   t_local = 16(mt&1)+4lg+r; dest lane (lg2=t_local>>3, lr2=lr), byte j=t_local&7
    int tl = 16 * (wid & 1) + 4 * lg;  // (wid^4)&1 == wid&1
#pragma unroll
    for (int r = 0; r < 4; ++r) {
      int t = tl + r;
      int lg2 = t >> 3, j = t & 7;
      *(unsigned short*)(smem +
        ((((wid >> 1) * 12 + nt) * 64 + lg2 * 16 + lr) << 4) + j * 2) = f2bf(a0[r]);
      *(unsigned short*)(smem +
        (((((wid ^ 4) >> 1) * 12 + nt) * 64 + lg2 * 16 + lr) << 4) + j * 2) = f2bf(a1[r]);
    }
  }
  __syncthreads();  // B3: V fragments visible

  // ---- PV: A-frag from pw via register shuffle; B-frag from LDS ----
  f32x4 o[12];
#pragma unroll
  for (int ht = 0; ht < 12; ++ht) o[ht] = zero;
#pragma unroll
  for (int tp = 0; tp < 4; ++tp) {
    if (tp <= (qt >> 1)) {
      union { unsigned d[4]; short8 v; } au;
#pragma unroll
      for (int i = 0; i < 4; ++i) {
        int sl = ((2 * (lg & 1) + (i >> 1)) << 4) | lr;
        unsigned lo = (unsigned)__shfl((int)pw[2 * tp][i & 1], sl);
        unsigned hi = (unsigned)__shfl((int)pw[2 * tp + 1][i & 1], sl);
        au.d[i] = (lg >> 1) ? hi : lo;
      }
      short8 a = au.v;
#pragma unroll
      for (int ht = 0; ht < 12; ++ht) {
        short8 bv = *(const short8*)(smem + (((tp * 12 + ht) * 64 + lane) << 4));
        o[ht] = __builtin_amdgcn_mfma_f32_16x16x32_bf16(a, bv, o[ht], 0, 0, 0);
      }
    }
  }

  // ---- store out fp32: lane holds O[16qt+4lg+r][16ht+lr] ----
  float* ob = out + (size_t)b * (TT * HH);
#pragma unroll
  for (int ht = 0; ht < 12; ++ht)
#pragma unroll
    for (int r = 0; r < 4; ++r)
      ob[(16 * qt + 4 * lg + r) * HH + 16 * ht + lr] = o[ht][r];
}

extern "C" void kernel_launch(void* const* d_in, const int* in_sizes, int n_in,
                              void* d_out, int out_size, void* d_ws, size_t ws_size,
                              hipStream_t stream) {
  const float* x  = (const float*)d_in[0];
  const float* Wq = (const float*)d_in[1];
  const float* Wk = (const float*)d_in[2];
  const float* Wv = (const float*)d_in[3];
  float* out = (float*)d_out;
  short* wsW = (short*)d_ws;  // 216 frags x 1KB = 221184 B
  int Bn = in_sizes[0] / (TT * EE);

  hipLaunchKernelGGL(pack_w, dim3(54), dim3(256), 0, stream, Wq, Wk, Wv, wsW);
  hipLaunchKernelGGL(head_fused, dim3(Bn), dim3(512), 49152, stream,
                     x, wsW, out);
}

// Round 5
// 257.854 us; speedup vs baseline: 2.1748x; 2.0493x over previous
//
#include <hip/hip_runtime.h>

// Problem constants
#define TT 128
#define EE 192
#define HH 192
#define SCALE_F 0.07216878364870322f
#define LOG2E_F 1.4426950408889634f

typedef float f32x4 __attribute__((ext_vector_type(4)));
typedef short short8 __attribute__((ext_vector_type(8)));

__device__ inline unsigned short f2bf(float x) {
  union { float f; unsigned u; } v; v.f = x;
  unsigned r = v.u + 0x7FFFu + ((v.u >> 16) & 1u);
  return (unsigned short)(r >> 16);
}
__device__ inline unsigned pack2bf(float a, float b) {
  return (unsigned)f2bf(a) | ((unsigned)f2bf(b) << 16);
}

// ---------------------------------------------------------------------------
// pack_w: W[h][e] fp32 -> frag-major bf16 in ws.
// frag f = widx*72 + tile*6 + es  (widx: 0=Q,1=K,2=V; tile=h/16; es=e/32)
// element: lane(lg,lr), j=0..7 -> W[16*tile+lr][32*es+8*lg+j]
// Each frag is 1KB contiguous: ws[(f*64+lane)*8 + j]
// ---------------------------------------------------------------------------
__global__ void pack_w(const float* __restrict__ Wq, const float* __restrict__ Wk,
                       const float* __restrict__ Wv, short* __restrict__ out) {
  int f = blockIdx.x * 4 + (threadIdx.x >> 6);  // 216 frags, grid 54 x 256
  int lane = threadIdx.x & 63, lg = lane >> 4, lr = lane & 15;
  int widx = f / 72, rem = f % 72, tile = rem / 6, es = rem % 6;
  const float* W = (widx == 0) ? Wq : ((widx == 1) ? Wk : Wv);
  const float* p = W + (16 * tile + lr) * EE + 32 * es + 8 * lg;
  float4 a = *(const float4*)p;
  float4 b = *(const float4*)(p + 4);
  short8 h;
  h[0] = (short)f2bf(a.x); h[1] = (short)f2bf(a.y);
  h[2] = (short)f2bf(a.z); h[3] = (short)f2bf(a.w);
  h[4] = (short)f2bf(b.x); h[5] = (short)f2bf(b.y);
  h[6] = (short)f2bf(b.z); h[7] = (short)f2bf(b.w);
  *(short8*)(out + ((size_t)f * 64 + lane) * 8) = h;
}

// ---------------------------------------------------------------------------
// Fused head kernel. Block = 1 batch, 512 thr (8 waves), 48KB LDS, 3 barriers.
// LDS holds K as QK^T A-fragments [kt 0..7][ha 0..5] (48 x 1KB), then (after
// B2) V as PV B-fragments [tp 0..3][ht 0..11] (48 x 1KB).
// Wave wid: q-tile qt=wid; staging m-tiles {wid, wid^4} x n-slab (wid>>2)*6.
// __launch_bounds__(512, 2): CUDA semantics min-2-blocks/CU -> 128 VGPR cap.
// (512,4) capped at 64 VGPR and spilled catastrophically in round 4.)
// ---------------------------------------------------------------------------
__global__ __launch_bounds__(512, 2)
void head_fused(const float* __restrict__ x, const short* __restrict__ wf,
                float* __restrict__ out) {
  extern __shared__ char smem[];  // 49152 B
  const int b = blockIdx.x;
  const int tid = threadIdx.x;
  const int wid = tid >> 6, lane = tid & 63, lg = lane >> 4, lr = lane & 15;
  const int qt = wid;
  const int ns0 = (wid >> 2) * 6;  // staging n-slab

  const short* wfq = wf;
  const short* wfk = wf + 72 * 64 * 8;
  const short* wfv = wf + 2 * 72 * 64 * 8;
  const f32x4 zero = {0.f, 0.f, 0.f, 0.f};

  // ---- x fragments: xq = rows 16*wid+lr (own q-rows), xo = rows 16*(wid^4)+lr
  const float* xb = x + (size_t)b * (TT * EE);
  short8 xq[6], xo[6];
#pragma unroll
  for (int es = 0; es < 6; ++es) {
    const float* p = xb + (16 * wid + lr) * EE + 32 * es + 8 * lg;
    float4 u = *(const float4*)p, v = *(const float4*)(p + 4);
    short8 h;
    h[0] = (short)f2bf(u.x); h[1] = (short)f2bf(u.y);
    h[2] = (short)f2bf(u.z); h[3] = (short)f2bf(u.w);
    h[4] = (short)f2bf(v.x); h[5] = (short)f2bf(v.y);
    h[6] = (short)f2bf(v.z); h[7] = (short)f2bf(v.w);
    xq[es] = h;
    const float* p2 = xb + (16 * (wid ^ 4) + lr) * EE + 32 * es + 8 * lg;
    float4 u2 = *(const float4*)p2, v2 = *(const float4*)(p2 + 4);
    short8 h2;
    h2[0] = (short)f2bf(u2.x); h2[1] = (short)f2bf(u2.y);
    h2[2] = (short)f2bf(u2.z); h2[3] = (short)f2bf(u2.w);
    h2[4] = (short)f2bf(v2.x); h2[5] = (short)f2bf(v2.y);
    h2[6] = (short)f2bf(v2.z); h2[7] = (short)f2bf(v2.w);
    xo[es] = h2;
  }

  // ---- Q^T then shuffle to QK B-fragments; wqp scoped to die early ----
  short8 qb[6];
  {
    unsigned wqp[12][2];
#pragma unroll
    for (int ht = 0; ht < 12; ++ht) {
      f32x4 a = zero;
#pragma unroll
      for (int es = 0; es < 6; ++es) {
        short8 wg = *(const short8*)(wfq + ((size_t)(ht * 6 + es) * 64 + lane) * 8);
        a = __builtin_amdgcn_mfma_f32_16x16x32_bf16(wg, xq[es], a, 0, 0, 0);
      }
      wqp[ht][0] = pack2bf(a[0], a[1]);
      wqp[ht][1] = pack2bf(a[2], a[3]);
    }
    // qb[ha]: lane j -> Q[16qt+lr][32ha+8lg+j]
#pragma unroll
    for (int ha = 0; ha < 6; ++ha) {
      union { unsigned d[4]; short8 v; } au;
#pragma unroll
      for (int i = 0; i < 4; ++i) {
        int sl = ((2 * (lg & 1) + (i >> 1)) << 4) | lr;
        unsigned v0 = (unsigned)__shfl((int)wqp[2 * ha][i & 1], sl);
        unsigned v1 = (unsigned)__shfl((int)wqp[2 * ha + 1][i & 1], sl);
        au.d[i] = (lg >> 1) ? v1 : v0;
      }
      qb[ha] = au.v;
    }
  }

  // ---- K staging: tiles (mt=wid, nt) with xq and (mt=wid^4, nt) with xo ----
#pragma unroll
  for (int n6 = 0; n6 < 6; ++n6) {
    int nt = ns0 + n6;
    f32x4 a0 = zero, a1 = zero;
#pragma unroll
    for (int es = 0; es < 6; ++es) {
      short8 wg = *(const short8*)(wfk + ((size_t)(nt * 6 + es) * 64 + lane) * 8);
      a0 = __builtin_amdgcn_mfma_f32_16x16x32_bf16(xq[es], wg, a0, 0, 0, 0);
      a1 = __builtin_amdgcn_mfma_f32_16x16x32_bf16(xo[es], wg, a1, 0, 0, 0);
    }
    // value K[16mt+4lg+r][16nt+lr] -> A-frag(kt=mt, ha=nt>>1):
    //   dest lane (lg2=2(nt&1)+(lr>>3), lr2=4lg+r), byte j=lr&7
    int lg2 = 2 * (nt & 1) + (lr >> 3), j = lr & 7;
#pragma unroll
    for (int r = 0; r < 4; ++r) {
      *(unsigned short*)(smem +
        (((wid * 6 + (nt >> 1)) * 64 + lg2 * 16 + 4 * lg + r) << 4) + j * 2) = f2bf(a0[r]);
      *(unsigned short*)(smem +
        ((((wid ^ 4) * 6 + (nt >> 1)) * 64 + lg2 * 16 + 4 * lg + r) << 4) + j * 2) = f2bf(a1[r]);
    }
  }
  __syncthreads();  // B1: K fragments visible

  // ---- QK^T (S^T = mfma(K, Q)): lane holds S^T[16kt+4lg+r][16qt+lr] ----
  unsigned pw[8][2];
  {
    f32x4 sa[8];
#pragma unroll
    for (int kt = 0; kt < 8; ++kt) sa[kt] = zero;
#pragma unroll
    for (int kt = 0; kt < 8; ++kt) {
      if (kt <= qt) {
#pragma unroll
        for (int ha = 0; ha < 6; ++ha) {
          short8 ka = *(const short8*)(smem + (((kt * 6 + ha) * 64 + lane) << 4));
          sa[kt] = __builtin_amdgcn_mfma_f32_16x16x32_bf16(ka, qb[ha], sa[kt], 0, 0, 0);
        }
      }
    }

    // ---- softmax over row q=16qt+lr (in-lane + 2 shfl_xor across lg) ----
    const float CSC = SCALE_F * LOG2E_F;
    float m = -INFINITY;
#pragma unroll
    for (int kt = 0; kt < 8; ++kt)
      if (kt <= qt) {
#pragma unroll
        for (int r = 0; r < 4; ++r) {
          float v = sa[kt][r] * CSC;
          if (kt == qt && 4 * lg + r > lr) v = -INFINITY;  // causal diagonal
          sa[kt][r] = v;
          m = fmaxf(m, v);
        }
      }
    m = fmaxf(m, __shfl_xor(m, 16));
    m = fmaxf(m, __shfl_xor(m, 32));
    float sum = 0.f;
#pragma unroll
    for (int kt = 0; kt < 8; ++kt)
      if (kt <= qt) {
#pragma unroll
        for (int r = 0; r < 4; ++r) {
          float p = exp2f(sa[kt][r] - m);
          sa[kt][r] = p;
          sum += p;
        }
      }
    sum += __shfl_xor(sum, 16);
    sum += __shfl_xor(sum, 32);
    const float rinv = 1.0f / sum;

#pragma unroll
    for (int kt = 0; kt < 8; ++kt) { pw[kt][0] = 0u; pw[kt][1] = 0u; }
#pragma unroll
    for (int kt = 0; kt < 8; ++kt)
      if (kt <= qt) {
        pw[kt][0] = pack2bf(sa[kt][0] * rinv, sa[kt][1] * rinv);
        pw[kt][1] = pack2bf(sa[kt][2] * rinv, sa[kt][3] * rinv);
      }
  }
  __syncthreads();  // B2: all K-fragment reads done; LDS reusable for V

  // ---- V staging into PV B-fragments [tp][ht] ----
#pragma unroll
  for (int n6 = 0; n6 < 6; ++n6) {
    int nt = ns0 + n6;
    f32x4 a0 = zero, a1 = zero;
#pragma unroll
    for (int es = 0; es < 6; ++es) {
      short8 wg = *(const short8*)(wfv + ((size_t)(nt * 6 + es) * 64 + lane) * 8);
      a0 = __builtin_amdgcn_mfma_f32_16x16x32_bf16(xq[es], wg, a0, 0, 0, 0);
      a1 = __builtin_amdgcn_mfma_f32_16x16x32_bf16(xo[es], wg, a1, 0, 0, 0);
    }
    // value V[16mt+4lg+r][16nt+lr] -> B-frag(tp=mt>>1, ht=nt):
    //   t_local = 16(mt&1)+4lg+r; dest lane (lg2=t_local>>3, lr2=lr), byte j=t_local&7
    int tl = 16 * (wid & 1) + 4 * lg;  // (wid^4)&1 == wid&1
#pragma unroll
    for (int r = 0; r < 4; ++r) {
      int t = tl + r;
      int lg2 = t >> 3, j = t & 7;
      *(unsigned short*)(smem +
        ((((wid >> 1) * 12 + nt) * 64 + lg2 * 16 + lr) << 4) + j * 2) = f2bf(a0[r]);
      *(unsigned short*)(smem +
        (((((wid ^ 4) >> 1) * 12 + nt) * 64 + lg2 * 16 + lr) << 4) + j * 2) = f2bf(a1[r]);
    }
  }
  __syncthreads();  // B3: V fragments visible

  // ---- PV: A-frag from pw via register shuffle; B-frag from LDS ----
  f32x4 o[12];
#pragma unroll
  for (int ht = 0; ht < 12; ++ht) o[ht] = zero;
#pragma unroll
  for (int tp = 0; tp < 4; ++tp) {
    if (tp <= (qt >> 1)) {
      union { unsigned d[4]; short8 v; } au;
#pragma unroll
      for (int i = 0; i < 4; ++i) {
        int sl = ((2 * (lg & 1) + (i >> 1)) << 4) | lr;
        unsigned lo = (unsigned)__shfl((int)pw[2 * tp][i & 1], sl);
        unsigned hi = (unsigned)__shfl((int)pw[2 * tp + 1][i & 1], sl);
        au.d[i] = (lg >> 1) ? hi : lo;
      }
      short8 a = au.v;
#pragma unroll
      for (int ht = 0; ht < 12; ++ht) {
        short8 bv = *(const short8*)(smem + (((tp * 12 + ht) * 64 + lane) << 4));
        o[ht] = __builtin_amdgcn_mfma_f32_16x16x32_bf16(a, bv, o[ht], 0, 0, 0);
      }
    }
  }

  // ---- store out fp32: lane holds O[16qt+4lg+r][16ht+lr] ----
  float* ob = out + (size_t)b * (TT * HH);
#pragma unroll
  for (int ht = 0; ht < 12; ++ht)
#pragma unroll
    for (int r = 0; r < 4; ++r)
      ob[(16 * qt + 4 * lg + r) * HH + 16 * ht + lr] = o[ht][r];
}

extern "C" void kernel_launch(void* const* d_in, const int* in_sizes, int n_in,
                              void* d_out, int out_size, void* d_ws, size_t ws_size,
                              hipStream_t stream) {
  const float* x  = (const float*)d_in[0];
  const float* Wq = (const float*)d_in[1];
  const float* Wk = (const float*)d_in[2];
  const float* Wv = (const float*)d_in[3];
  float* out = (float*)d_out;
  short* wsW = (short*)d_ws;  // 216 frags x 1KB = 221184 B
  int Bn = in_sizes[0] / (TT * EE);

  hipLaunchKernelGGL(pack_w, dim3(54), dim3(256), 0, stream, Wq, Wk, Wv, wsW);
  hipLaunchKernelGGL(head_fused, dim3(Bn), dim3(512), 49152, stream,
                     x, wsW, out);
}